// Round 1
// baseline (161.224 us; speedup 1.0000x reference)
//
#include <hip/hip_runtime.h>

#define NVOX  160000
#define KOFF  27
#define EPSV  1e-5f
#define SLOPE 0.01f
#define NBLK  2500    // conv blocks: 2500 * 256 thr = 10,000 waves * 16 vox
#define SPAD  16      // stats slot stride (floats) -> 64 B, own cache line per slot

using bf16x8 = __attribute__((ext_vector_type(8))) __bf16;
using f32x4  = __attribute__((ext_vector_type(4))) float;
using i32x4  = __attribute__((ext_vector_type(4))) int;
using u16    = unsigned short;

// Dtype evidence (prior rounds): feat/weight/out/gamma are all f32.

// ---------------------------------------------------------------------------
// Pack W[27][32][32] f32 into MFMA B-fragment order (bf16), and zero the
// padded stats accumulators (stream order guarantees this completes before
// conv_f32's atomics).
// frag (k,f): couts f*16..f*16+15; lane L reg j holds B[c=(L>>4)*8+j][d=f*16+(L&15)]
// ---------------------------------------------------------------------------
__global__ void pack_weights(const float* __restrict__ w, u16* __restrict__ wp,
                             float* __restrict__ stats) {
    int tid = blockIdx.x * blockDim.x + threadIdx.x;   // 27648
    if (blockIdx.x == 0) {
        // zero 64 slots * 16 floats = 4 KB
        int t = threadIdx.x;
        stats[t] = 0.f; stats[256 + t] = 0.f; stats[512 + t] = 0.f; stats[768 + t] = 0.f;
    }
    if (tid >= KOFF * 2 * 64 * 8) return;
    int j = tid & 7;
    int L = (tid >> 3) & 63;
    int f = (tid >> 9) & 1;
    int k = tid >> 10;
    int c = ((L >> 4) << 3) + j;
    int d = (f << 4) + (L & 15);
    __bf16 b = (__bf16)w[(k * 32 + c) * 32 + d];
    wp[tid] = __builtin_bit_cast(u16, b);
}

// ---------------------------------------------------------------------------
// Sparse conv via MFMA + fused BN-stats partials. Each wave owns 16 voxels.
// Phase 0: cooperative coalesced stage of the block's 64 neighbor rows
//          (64*27 ints) into LDS — removes id[27] VGPRs and the 4x redundant
//          per-lane row loads of the previous version.
// Phase 1: 3 batches of 9 offsets; wave-uniform ballot skip per offset;
//          taken offsets: 2 clamped dwordx4 gathers -> bf16 frag -> 2 MFMAs.
// Epilogue: conv -> d_out; per-channel sum/sumsq reduced block-wide, then
//           atomicAdd into padded stats slots (64 B apart -> no L2 line
//           serialization). reduce_stats dispatch is gone.
// ---------------------------------------------------------------------------
__global__ __launch_bounds__(256) void conv_f32(
    const float* __restrict__ feat,     // [N][32]
    const int*  __restrict__ nbr,       // [N][27]
    const i32x4* __restrict__ wp,       // packed B-frags
    float* __restrict__ out,            // [N][32] (d_out)
    float* __restrict__ stats)          // [64][SPAD]
{
    const int lane  = threadIdx.x & 63;
    const int wid   = (blockIdx.x * 256 + threadIdx.x) >> 6;   // 0..9999
    const int vbase = wid * 16;
    const int m = lane & 15;
    const int q = lane >> 4;

    __shared__ int   nlds[64 * KOFF];   // 6912 B
    __shared__ float red[4][64];        // 1024 B

    // ---- phase 0: coalesced stage of 64 neighbor rows into LDS ----
    {
        const int* src = nbr + (size_t)(blockIdx.x * 64) * KOFF;
#pragma unroll
        for (int i = 0; i < 7; ++i) {
            int idx = threadIdx.x + i * 256;
            if (idx < 64 * KOFF) nlds[idx] = src[idx];
        }
    }
    __syncthreads();

    const int* myrow = nlds + ((threadIdx.x >> 6) * 16 + m) * KOFF;

    f32x4 acc0 = {}, acc1 = {};

    // ---- phase 1: 3 batches of 9, ballot-gated gathers then drain+MFMA ----
#pragma unroll
    for (int b = 0; b < 3; ++b) {
        f32x4 lo[9], hi[9];
        int   idb[9];
#pragma unroll
        for (int j = 0; j < 9; ++j) {
            int k = b * 9 + j;
            idb[j] = myrow[k];
            if (__ballot(idb[j] >= 0)) {           // wave-uniform scalar branch
                int v_id = idb[j];
                int safe = v_id >= 0 ? v_id : 0;   // invalid -> hot row 0 (L1)
                const f32x4* fp = (const f32x4*)(feat + (size_t)safe * 32 + q * 8);
                lo[j] = fp[0];
                hi[j] = fp[1];
            }
        }
#pragma unroll
        for (int j = 0; j < 9; ++j) {
            int k = b * 9 + j;
            if (__ballot(idb[j] >= 0)) {
                bf16x8 t;
#pragma unroll
                for (int jj = 0; jj < 4; ++jj) {
                    t[jj]     = (__bf16)lo[j][jj];
                    t[4 + jj] = (__bf16)hi[j][jj];
                }
                bf16x8 z = {};
                bf16x8 a = (idb[j] < 0) ? z : t;
                i32x4 b0r = wp[(k * 2 + 0) * 64 + lane];
                i32x4 b1r = wp[(k * 2 + 1) * 64 + lane];
                bf16x8 b0 = __builtin_bit_cast(bf16x8, b0r);
                bf16x8 b1 = __builtin_bit_cast(bf16x8, b1r);
                acc0 = __builtin_amdgcn_mfma_f32_16x16x32_bf16(a, b0, acc0, 0, 0, 0);
                acc1 = __builtin_amdgcn_mfma_f32_16x16x32_bf16(a, b1, acc1, 0, 0, 0);
            }
        }
    }

    // ---- epilogue: store conv + per-channel stats ----
    // C/D: row(voxel) = q*4 + r, col(cout) = m (+16 for acc1)
    float s0 = 0, s1 = 0, sq0 = 0, sq1 = 0;
#pragma unroll
    for (int r = 0; r < 4; ++r) {
        int v = vbase + q * 4 + r;
        float x0 = acc0[r], x1 = acc1[r];
        s0 += x0; sq0 += x0 * x0;
        s1 += x1; sq1 += x1 * x1;
        out[v * 32 + m]      = x0;
        out[v * 32 + 16 + m] = x1;
    }
    // reduce over q (lanes sharing m)
    s0  += __shfl_xor(s0, 16, 64);  s0  += __shfl_xor(s0, 32, 64);
    s1  += __shfl_xor(s1, 16, 64);  s1  += __shfl_xor(s1, 32, 64);
    sq0 += __shfl_xor(sq0, 16, 64); sq0 += __shfl_xor(sq0, 32, 64);
    sq1 += __shfl_xor(sq1, 16, 64); sq1 += __shfl_xor(sq1, 32, 64);

    int w = threadIdx.x >> 6;
    if (lane < 16) {
        red[w][m]      = s0;   // sum, ch m
        red[w][16 + m] = s1;   // sum, ch 16+m
        red[w][32 + m] = sq0;  // sumsq, ch m
        red[w][48 + m] = sq1;  // sumsq, ch 16+m
    }
    __syncthreads();
    if (threadIdx.x < 64) {
        int t = threadIdx.x;
        float v = red[0][t] + red[1][t] + red[2][t] + red[3][t];
        atomicAdd(&stats[(size_t)t * SPAD], v);   // own cache line per slot
    }
}

// ---------------------------------------------------------------------------
// BN + LeakyReLU over d_out, in place; scale/shift derived per block from
// the padded stats slots (4 KB, L2-broadcast).
// ---------------------------------------------------------------------------
__global__ __launch_bounds__(256) void apply_bn(
    f32x4* __restrict__ o, const float* __restrict__ stats,
    const float* __restrict__ gamma, const float* __restrict__ beta)
{
    __shared__ float s[64];
    int t = threadIdx.x;
    if (t < 32) {
        float mean = stats[(size_t)t * SPAD] * (1.f / NVOX);
        float var  = stats[(size_t)(32 + t) * SPAD] * (1.f / NVOX) - mean * mean;
        float rstd = rsqrtf(var + EPSV);
        float scale = gamma[t] * rstd;
        s[t]      = scale;
        s[32 + t] = beta[t] - mean * scale;
    }
    __syncthreads();
    int i = blockIdx.x * 256 + t;
#pragma unroll
    for (int rep = 0; rep < 2; ++rep) {
        int i2 = i * 2 + rep;               // 1,280,000 vec4 total
        f32x4 v = o[i2];
        int c0 = (i2 & 7) * 4;
        f32x4 r;
#pragma unroll
        for (int j = 0; j < 4; ++j) {
            float y = v[j] * s[c0 + j] + s[32 + c0 + j];
            r[j] = (y >= 0.f) ? y : SLOPE * y;
        }
        o[i2] = r;
    }
}

// ---------------------------------------------------------------------------
extern "C" void kernel_launch(void* const* d_in, const int* in_sizes, int n_in,
                              void* d_out, int out_size, void* d_ws, size_t ws_size,
                              hipStream_t stream) {
    const float* feat  = (const float*)d_in[0];  // [N][32] f32
    const int*   nbr   = (const int*)d_in[1];    // [N][27] int32
    const float* w     = (const float*)d_in[2];  // [27][32][32] f32
    // d_in[3] = bias: cancels exactly in BN — unused
    const float* gamma = (const float*)d_in[4];
    const float* beta  = (const float*)d_in[5];

    // ws layout (avoid dynamic-indexed local arrays — round-4 scratch lesson):
    char* ws = (char*)d_ws;
    u16*   wp    = (u16*)ws;                     // 55,296 B
    float* stats = (float*)(ws + 57344);         // 64 slots * 64 B = 4096 B

    pack_weights<<<108, 256, 0, stream>>>(w, wp, stats);
    conv_f32<<<NBLK, 256, 0, stream>>>(feat, nbr, (const i32x4*)wp,
                                       (float*)d_out, stats);
    apply_bn<<<2500, 256, 0, stream>>>((f32x4*)d_out, stats, gamma, beta);
}

// Round 2
// 123.147 us; speedup vs baseline: 1.3092x; 1.3092x over previous
//
#include <hip/hip_runtime.h>

#define NVOX  160000
#define KOFF  27
#define EPSV  1e-5f
#define SLOPE 0.01f
#define NBLK  2500    // conv blocks: 2500*256 = 10,000 waves * 16 vox
#define NCOPY 8       // stats copies per channel-slot (chain depth 2500/8=313)
#define SPAD  16      // floats per copy slot -> 64 B, own cache line

using bf16x8 = __attribute__((ext_vector_type(8))) __bf16;
using f32x4  = __attribute__((ext_vector_type(4))) float;
using i32x4  = __attribute__((ext_vector_type(4))) int;
using u16    = unsigned short;
typedef __attribute__((ext_vector_type(4), aligned(4))) int i32x4u;
typedef __attribute__((ext_vector_type(2), aligned(4))) int i32x2u;

// Dtype evidence (prior rounds): feat/weight/out/gamma are all f32.
// Round-1 lesson: moving nbr ids to LDS let the compiler sink the feature
// gathers into their consumers (VGPR 150->60) -> MLP collapse, conv 74us.
// Keep id[27]+lo/hi[9] in registers (round-0 structure, proven 123us total).

// ---------------------------------------------------------------------------
// Pack W[27][32][32] f32 into MFMA B-fragment order (bf16); zero the stats
// accumulators (stream order guarantees completion before conv's atomics).
// frag (k,f): couts f*16..f*16+15; lane L reg j holds B[c=(L>>4)*8+j][d=f*16+(L&15)]
// ---------------------------------------------------------------------------
__global__ void pack_weights(const float* __restrict__ w, u16* __restrict__ wp,
                             float* __restrict__ stats) {
    int tid = blockIdx.x * blockDim.x + threadIdx.x;   // 27648
    if (blockIdx.x < 8) {
        // zero 64 slots * 8 copies * 16 floats = 8192 floats (32 KB)
        int t = blockIdx.x * 1024 + threadIdx.x;
        stats[t] = 0.f; stats[t + 256] = 0.f; stats[t + 512] = 0.f; stats[t + 768] = 0.f;
    }
    if (tid >= KOFF * 2 * 64 * 8) return;
    int j = tid & 7;
    int L = (tid >> 3) & 63;
    int f = (tid >> 9) & 1;
    int k = tid >> 10;
    int c = ((L >> 4) << 3) + j;
    int d = (f << 4) + (L & 15);
    __bf16 b = (__bf16)w[(k * 32 + c) * 32 + d];
    wp[tid] = __builtin_bit_cast(u16, b);
}

// ---------------------------------------------------------------------------
// Sparse conv via MFMA + fused BN-stats. Each wave owns 16 voxels.
// Phase 0: preload 27 neighbor ids per lane (contiguous row, 7 vector loads).
// Phase 1: 3 batches of 9 offsets; wave-uniform ballot skip per offset;
//          taken offsets: 2 clamped dwordx4 gathers -> bf16 frag -> 2 MFMAs.
// Epilogue: conv -> d_out; block-wide channel sums -> atomicAdd into
//           (channel, blockIdx&7) padded slots: chain depth 313/address,
//           hidden under staggered block retirement.
// ---------------------------------------------------------------------------
__global__ __launch_bounds__(256) void conv_f32(
    const float* __restrict__ feat,     // [N][32]
    const int*  __restrict__ nbr,       // [N][27]
    const i32x4* __restrict__ wp,       // packed B-frags
    float* __restrict__ out,            // [N][32] (d_out)
    float* __restrict__ stats)          // [64][NCOPY][SPAD]
{
    const int lane  = threadIdx.x & 63;
    const int wid   = (blockIdx.x * 256 + threadIdx.x) >> 6;   // 0..9999
    const int vbase = wid * 16;
    const int m = lane & 15;
    const int q = lane >> 4;

    // ---- phase 0: this lane's full neighbor row (registers!) ----
    const int* row = nbr + (size_t)(vbase + m) * KOFF;
    int id[27];
    *(i32x4u*)(id +  0) = *(const i32x4u*)(row +  0);
    *(i32x4u*)(id +  4) = *(const i32x4u*)(row +  4);
    *(i32x4u*)(id +  8) = *(const i32x4u*)(row +  8);
    *(i32x4u*)(id + 12) = *(const i32x4u*)(row + 12);
    *(i32x4u*)(id + 16) = *(const i32x4u*)(row + 16);
    *(i32x4u*)(id + 20) = *(const i32x4u*)(row + 20);
    *(i32x2u*)(id + 24) = *(const i32x2u*)(row + 24);
    id[26] = row[26];

    f32x4 acc0 = {}, acc1 = {};

    // ---- phase 1: 3 batches of 9, ballot-gated gathers then drain+MFMA ----
#pragma unroll
    for (int b = 0; b < 3; ++b) {
        f32x4 lo[9], hi[9];
#pragma unroll
        for (int j = 0; j < 9; ++j) {
            int k = b * 9 + j;
            if (__ballot(id[k] >= 0)) {            // wave-uniform scalar branch
                int v_id = id[k];
                int safe = v_id >= 0 ? v_id : 0;   // invalid -> hot row 0 (L1)
                const f32x4* fp = (const f32x4*)(feat + (size_t)safe * 32 + q * 8);
                lo[j] = fp[0];
                hi[j] = fp[1];
            }
        }
#pragma unroll
        for (int j = 0; j < 9; ++j) {
            int k = b * 9 + j;
            if (__ballot(id[k] >= 0)) {
                bf16x8 t;
#pragma unroll
                for (int jj = 0; jj < 4; ++jj) {
                    t[jj]     = (__bf16)lo[j][jj];
                    t[4 + jj] = (__bf16)hi[j][jj];
                }
                bf16x8 z = {};
                bf16x8 a = (id[k] < 0) ? z : t;
                i32x4 b0r = wp[(k * 2 + 0) * 64 + lane];
                i32x4 b1r = wp[(k * 2 + 1) * 64 + lane];
                bf16x8 b0 = __builtin_bit_cast(bf16x8, b0r);
                bf16x8 b1 = __builtin_bit_cast(bf16x8, b1r);
                acc0 = __builtin_amdgcn_mfma_f32_16x16x32_bf16(a, b0, acc0, 0, 0, 0);
                acc1 = __builtin_amdgcn_mfma_f32_16x16x32_bf16(a, b1, acc1, 0, 0, 0);
            }
        }
    }

    // ---- epilogue: store conv + per-channel stats ----
    // C/D: row(voxel) = q*4 + r, col(cout) = m (+16 for acc1)
    float s0 = 0, s1 = 0, sq0 = 0, sq1 = 0;
#pragma unroll
    for (int r = 0; r < 4; ++r) {
        int v = vbase + q * 4 + r;
        float x0 = acc0[r], x1 = acc1[r];
        s0 += x0; sq0 += x0 * x0;
        s1 += x1; sq1 += x1 * x1;
        out[v * 32 + m]      = x0;
        out[v * 32 + 16 + m] = x1;
    }
    // reduce over q (lanes sharing m)
    s0  += __shfl_xor(s0, 16, 64);  s0  += __shfl_xor(s0, 32, 64);
    s1  += __shfl_xor(s1, 16, 64);  s1  += __shfl_xor(s1, 32, 64);
    sq0 += __shfl_xor(sq0, 16, 64); sq0 += __shfl_xor(sq0, 32, 64);
    sq1 += __shfl_xor(sq1, 16, 64); sq1 += __shfl_xor(sq1, 32, 64);

    __shared__ float red[4][64];
    int w = threadIdx.x >> 6;
    if (lane < 16) {
        red[w][m]      = s0;   // sum, ch m
        red[w][16 + m] = s1;   // sum, ch 16+m
        red[w][32 + m] = sq0;  // sumsq, ch m
        red[w][48 + m] = sq1;  // sumsq, ch 16+m
    }
    __syncthreads();
    if (threadIdx.x < 64) {
        int t = threadIdx.x;
        float v = red[0][t] + red[1][t] + red[2][t] + red[3][t];
        // slot (t, blockIdx&7), own 64 B line -> parallel chains of depth 313
        atomicAdd(&stats[((size_t)t * NCOPY + (blockIdx.x & (NCOPY - 1))) * SPAD], v);
    }
}

// ---------------------------------------------------------------------------
// BN + LeakyReLU over d_out, in place; scale/shift derived per block from
// the 8-copy stats slots (32 KB, L2-broadcast) — saves a reduce dispatch.
// ---------------------------------------------------------------------------
__global__ __launch_bounds__(256) void apply_bn(
    f32x4* __restrict__ o, const float* __restrict__ stats,
    const float* __restrict__ gamma, const float* __restrict__ beta)
{
    __shared__ float s[64];
    int t = threadIdx.x;
    if (t < 32) {
        float sum = 0.f, sumsq = 0.f;
#pragma unroll
        for (int c = 0; c < NCOPY; ++c) {
            sum   += stats[((size_t)t * NCOPY + c) * SPAD];
            sumsq += stats[((size_t)(32 + t) * NCOPY + c) * SPAD];
        }
        float mean = sum * (1.f / NVOX);
        float var  = sumsq * (1.f / NVOX) - mean * mean;
        float rstd = rsqrtf(var + EPSV);
        float scale = gamma[t] * rstd;
        s[t]      = scale;
        s[32 + t] = beta[t] - mean * scale;
    }
    __syncthreads();
    int i = blockIdx.x * 256 + t;
#pragma unroll
    for (int rep = 0; rep < 2; ++rep) {
        int i2 = i * 2 + rep;               // 1,280,000 vec4 total
        f32x4 v = o[i2];
        int c0 = (i2 & 7) * 4;
        f32x4 r;
#pragma unroll
        for (int j = 0; j < 4; ++j) {
            float y = v[j] * s[c0 + j] + s[32 + c0 + j];
            r[j] = (y >= 0.f) ? y : SLOPE * y;
        }
        o[i2] = r;
    }
}

// ---------------------------------------------------------------------------
extern "C" void kernel_launch(void* const* d_in, const int* in_sizes, int n_in,
                              void* d_out, int out_size, void* d_ws, size_t ws_size,
                              hipStream_t stream) {
    const float* feat  = (const float*)d_in[0];  // [N][32] f32
    const int*   nbr   = (const int*)d_in[1];    // [N][27] int32
    const float* w     = (const float*)d_in[2];  // [27][32][32] f32
    // d_in[3] = bias: cancels exactly in BN — unused
    const float* gamma = (const float*)d_in[4];
    const float* beta  = (const float*)d_in[5];

    // ws layout (avoid dynamic-indexed local arrays — prior scratch lesson):
    char* ws = (char*)d_ws;
    u16*   wp    = (u16*)ws;                     // 55,296 B
    float* stats = (float*)(ws + 57344);         // 64*8 slots * 64 B = 32,768 B

    pack_weights<<<108, 256, 0, stream>>>(w, wp, stats);
    conv_f32<<<NBLK, 256, 0, stream>>>(feat, nbr, (const i32x4*)wp,
                                       (float*)d_out, stats);
    apply_bn<<<2500, 256, 0, stream>>>((f32x4*)d_out, stats, gamma, beta);
}

// Round 3
// 119.308 us; speedup vs baseline: 1.3513x; 1.0322x over previous
//
#include <hip/hip_runtime.h>

#define NVOX  160000
#define KOFF  27
#define EPSV  1e-5f
#define SLOPE 0.01f
#define NBLK  2500    // conv blocks: 2500*256 = 10,000 waves * 16 vox
#define NCOPY 8       // stats copies per channel-slot (chain depth 2500/8=313)
#define SPAD  16      // floats per copy slot -> 64 B, own cache line
#define NXCD  8

using bf16x8 = __attribute__((ext_vector_type(8))) __bf16;
using f32x4  = __attribute__((ext_vector_type(4))) float;
using i32x4  = __attribute__((ext_vector_type(4))) int;
using u16    = unsigned short;
typedef __attribute__((ext_vector_type(4), aligned(4))) int i32x4u;
typedef __attribute__((ext_vector_type(2), aligned(4))) int i32x2u;

// Dtype evidence (prior rounds): feat/weight/out/gamma are all f32.
// Round-1 lesson: ids in LDS let the compiler sink gathers into consumers
// (VGPR 150->60, MLP collapse, conv 74us). Keep id[27]+lo/hi batch in regs.
// Round-2: atomic 8-copy stats fusion works (123us, reduce dispatch gone).
// Round-3 levers: batch 9->7 + launch_bounds(256,4) => VGPR<=128 (4 w/SIMD);
//                 bijective XCD-chunked swizzle => per-XCD L2-resident feat.

// ---------------------------------------------------------------------------
// Pack W[27][32][32] f32 into MFMA B-fragment order (bf16); zero the stats
// accumulators (stream order guarantees completion before conv's atomics).
// frag (k,f): couts f*16..f*16+15; lane L reg j holds B[c=(L>>4)*8+j][d=f*16+(L&15)]
// ---------------------------------------------------------------------------
__global__ void pack_weights(const float* __restrict__ w, u16* __restrict__ wp,
                             float* __restrict__ stats) {
    int tid = blockIdx.x * blockDim.x + threadIdx.x;   // 27648
    if (blockIdx.x < 8) {
        // zero 64 slots * 8 copies * 16 floats = 8192 floats (32 KB)
        int t = blockIdx.x * 1024 + threadIdx.x;
        stats[t] = 0.f; stats[t + 256] = 0.f; stats[t + 512] = 0.f; stats[t + 768] = 0.f;
    }
    if (tid >= KOFF * 2 * 64 * 8) return;
    int j = tid & 7;
    int L = (tid >> 3) & 63;
    int f = (tid >> 9) & 1;
    int k = tid >> 10;
    int c = ((L >> 4) << 3) + j;
    int d = (f << 4) + (L & 15);
    __bf16 b = (__bf16)w[(k * 32 + c) * 32 + d];
    wp[tid] = __builtin_bit_cast(u16, b);
}

// ---------------------------------------------------------------------------
// Sparse conv via MFMA + fused BN-stats. Each wave owns 16 voxels.
// Phase 0: preload 27 neighbor ids per lane (contiguous row, 7 vector loads).
// Phase 1: 4 batches (7,7,7,6 offsets); wave-uniform ballot skip per offset;
//          taken offsets: 2 clamped dwordx4 gathers -> bf16 frag -> 2 MFMAs.
// Epilogue: conv -> d_out; block-wide channel sums -> atomicAdd into
//           (channel, blockIdx&7) padded slots.
// ---------------------------------------------------------------------------
__global__ __launch_bounds__(256, 4) void conv_f32(
    const float* __restrict__ feat,     // [N][32]
    const int*  __restrict__ nbr,       // [N][27]
    const i32x4* __restrict__ wp,       // packed B-frags
    float* __restrict__ out,            // [N][32] (d_out)
    float* __restrict__ stats)          // [64][NCOPY][SPAD]
{
    // ---- bijective XCD-chunked swizzle: each XCD gets a contiguous range ->
    //      sliding feat gather window (~2.6 MB) stays resident in its 4MB L2.
    int bid;
    {
        const int qc = NBLK / NXCD;          // 312
        const int rc = NBLK % NXCD;          // 4
        int xcd = blockIdx.x % NXCD;
        int idx = blockIdx.x / NXCD;
        int start = (xcd < rc) ? xcd * (qc + 1) : rc * (qc + 1) + (xcd - rc) * qc;
        bid = start + idx;
    }

    const int lane  = threadIdx.x & 63;
    const int wid   = (bid * 256 + threadIdx.x) >> 6;   // 0..9999 (permuted)
    const int vbase = wid * 16;
    const int m = lane & 15;
    const int q = lane >> 4;

    // ---- phase 0: this lane's full neighbor row (registers!) ----
    const int* row = nbr + (size_t)(vbase + m) * KOFF;
    int id[27];
    *(i32x4u*)(id +  0) = *(const i32x4u*)(row +  0);
    *(i32x4u*)(id +  4) = *(const i32x4u*)(row +  4);
    *(i32x4u*)(id +  8) = *(const i32x4u*)(row +  8);
    *(i32x4u*)(id + 12) = *(const i32x4u*)(row + 12);
    *(i32x4u*)(id + 16) = *(const i32x4u*)(row + 16);
    *(i32x4u*)(id + 20) = *(const i32x4u*)(row + 20);
    *(i32x2u*)(id + 24) = *(const i32x2u*)(row + 24);
    id[26] = row[26];

    f32x4 acc0 = {}, acc1 = {};

    // ---- phase 1: 4 batches of {7,7,7,6}, ballot-gated issue then drain ----
#pragma unroll
    for (int b = 0; b < 4; ++b) {
        const int base = b * 7;
        const int cnt  = (b == 3) ? 6 : 7;
        f32x4 lo[7], hi[7];
#pragma unroll
        for (int j = 0; j < 7; ++j) {
            if (j < cnt) {
                int k = base + j;
                if (__ballot(id[k] >= 0)) {        // wave-uniform scalar branch
                    int v_id = id[k];
                    int safe = v_id >= 0 ? v_id : 0;   // invalid -> hot row 0
                    const f32x4* fp = (const f32x4*)(feat + (size_t)safe * 32 + q * 8);
                    lo[j] = fp[0];
                    hi[j] = fp[1];
                }
            }
        }
#pragma unroll
        for (int j = 0; j < 7; ++j) {
            if (j < cnt) {
                int k = base + j;
                if (__ballot(id[k] >= 0)) {
                    bf16x8 t;
#pragma unroll
                    for (int jj = 0; jj < 4; ++jj) {
                        t[jj]     = (__bf16)lo[j][jj];
                        t[4 + jj] = (__bf16)hi[j][jj];
                    }
                    bf16x8 z = {};
                    bf16x8 a = (id[k] < 0) ? z : t;
                    i32x4 b0r = wp[(k * 2 + 0) * 64 + lane];
                    i32x4 b1r = wp[(k * 2 + 1) * 64 + lane];
                    bf16x8 b0 = __builtin_bit_cast(bf16x8, b0r);
                    bf16x8 b1 = __builtin_bit_cast(bf16x8, b1r);
                    acc0 = __builtin_amdgcn_mfma_f32_16x16x32_bf16(a, b0, acc0, 0, 0, 0);
                    acc1 = __builtin_amdgcn_mfma_f32_16x16x32_bf16(a, b1, acc1, 0, 0, 0);
                }
            }
        }
    }

    // ---- epilogue: store conv + per-channel stats ----
    // C/D: row(voxel) = q*4 + r, col(cout) = m (+16 for acc1)
    float s0 = 0, s1 = 0, sq0 = 0, sq1 = 0;
#pragma unroll
    for (int r = 0; r < 4; ++r) {
        int v = vbase + q * 4 + r;
        float x0 = acc0[r], x1 = acc1[r];
        s0 += x0; sq0 += x0 * x0;
        s1 += x1; sq1 += x1 * x1;
        out[v * 32 + m]      = x0;
        out[v * 32 + 16 + m] = x1;
    }
    // reduce over q (lanes sharing m)
    s0  += __shfl_xor(s0, 16, 64);  s0  += __shfl_xor(s0, 32, 64);
    s1  += __shfl_xor(s1, 16, 64);  s1  += __shfl_xor(s1, 32, 64);
    sq0 += __shfl_xor(sq0, 16, 64); sq0 += __shfl_xor(sq0, 32, 64);
    sq1 += __shfl_xor(sq1, 16, 64); sq1 += __shfl_xor(sq1, 32, 64);

    __shared__ float red[4][64];
    int w = threadIdx.x >> 6;
    if (lane < 16) {
        red[w][m]      = s0;   // sum, ch m
        red[w][16 + m] = s1;   // sum, ch 16+m
        red[w][32 + m] = sq0;  // sumsq, ch m
        red[w][48 + m] = sq1;  // sumsq, ch 16+m
    }
    __syncthreads();
    if (threadIdx.x < 64) {
        int t = threadIdx.x;
        float v = red[0][t] + red[1][t] + red[2][t] + red[3][t];
        // slot (t, bid&7), own 64 B line -> parallel chains of depth ~313
        atomicAdd(&stats[((size_t)t * NCOPY + (bid & (NCOPY - 1))) * SPAD], v);
    }
}

// ---------------------------------------------------------------------------
// BN + LeakyReLU over d_out, in place; scale/shift derived per block from
// the 8-copy stats slots (32 KB, L2-broadcast) — saves a reduce dispatch.
// ---------------------------------------------------------------------------
__global__ __launch_bounds__(256) void apply_bn(
    f32x4* __restrict__ o, const float* __restrict__ stats,
    const float* __restrict__ gamma, const float* __restrict__ beta)
{
    __shared__ float s[64];
    int t = threadIdx.x;
    if (t < 32) {
        float sum = 0.f, sumsq = 0.f;
#pragma unroll
        for (int c = 0; c < NCOPY; ++c) {
            sum   += stats[((size_t)t * NCOPY + c) * SPAD];
            sumsq += stats[((size_t)(32 + t) * NCOPY + c) * SPAD];
        }
        float mean = sum * (1.f / NVOX);
        float var  = sumsq * (1.f / NVOX) - mean * mean;
        float rstd = rsqrtf(var + EPSV);
        float scale = gamma[t] * rstd;
        s[t]      = scale;
        s[32 + t] = beta[t] - mean * scale;
    }
    __syncthreads();
    int i = blockIdx.x * 256 + t;
#pragma unroll
    for (int rep = 0; rep < 2; ++rep) {
        int i2 = i * 2 + rep;               // 1,280,000 vec4 total
        f32x4 v = o[i2];
        int c0 = (i2 & 7) * 4;
        f32x4 r;
#pragma unroll
        for (int j = 0; j < 4; ++j) {
            float y = v[j] * s[c0 + j] + s[32 + c0 + j];
            r[j] = (y >= 0.f) ? y : SLOPE * y;
        }
        o[i2] = r;
    }
}

// ---------------------------------------------------------------------------
extern "C" void kernel_launch(void* const* d_in, const int* in_sizes, int n_in,
                              void* d_out, int out_size, void* d_ws, size_t ws_size,
                              hipStream_t stream) {
    const float* feat  = (const float*)d_in[0];  // [N][32] f32
    const int*   nbr   = (const int*)d_in[1];    // [N][27] int32
    const float* w     = (const float*)d_in[2];  // [27][32][32] f32
    // d_in[3] = bias: cancels exactly in BN — unused
    const float* gamma = (const float*)d_in[4];
    const float* beta  = (const float*)d_in[5];

    // ws layout (avoid dynamic-indexed local arrays — prior scratch lesson):
    char* ws = (char*)d_ws;
    u16*   wp    = (u16*)ws;                     // 55,296 B
    float* stats = (float*)(ws + 57344);         // 64*8 slots * 64 B = 32,768 B

    pack_weights<<<108, 256, 0, stream>>>(w, wp, stats);
    conv_f32<<<NBLK, 256, 0, stream>>>(feat, nbr, (const i32x4*)wp,
                                       (float*)d_out, stats);
    apply_bn<<<2500, 256, 0, stream>>>((f32x4*)d_out, stats, gamma, beta);
}

// Round 4
// 117.633 us; speedup vs baseline: 1.3706x; 1.0142x over previous
//
#include <hip/hip_runtime.h>

#define NVOX  160000
#define KOFF  27
#define EPSV  1e-5f
#define SLOPE 0.01f
#define NBLK  2500    // conv blocks: 2500*256 = 10,000 waves * 16 vox
#define NCOPY 8       // stats copies per channel-slot (chain depth 2500/8=313)
#define SPAD  16      // floats per copy slot -> 64 B, own cache line
#define NXCD  8

using bf16x8 = __attribute__((ext_vector_type(8))) __bf16;
using f32x4  = __attribute__((ext_vector_type(4))) float;
using i32x4  = __attribute__((ext_vector_type(4))) int;
using u16    = unsigned short;
typedef __attribute__((ext_vector_type(4), aligned(4))) int i32x4u;
typedef __attribute__((ext_vector_type(2), aligned(4))) int i32x2u;

// Dtype evidence (prior rounds): feat/weight/out/gamma are all f32.
// Round-1 lesson: ids in LDS let the compiler sink gathers into consumers
// (VGPR 150->60, MLP collapse, conv 74us). Keep id[27]+lo/hi batch in regs.
// Round-2: atomic 8-copy stats fusion works (123us).
// Round-3: batch-7 + launch_bounds(256,4) + XCD-chunked conv swizzle: 119.3us.
// Topology is uniform-random (p=1.9%/neighbor) -> ~8 of 27 offsets taken per
// 16-voxel wave; ballot-skip already exploits this.
// Round-4: apply_bn gets the SAME chunked swizzle so each block reads the
// d_out chunk produced on its own XCD (local L2 hit instead of LLC/HBM).

// ---------------------------------------------------------------------------
// Bijective XCD-chunked swizzle (NBLK blocks over NXCD XCDs): round-robin
// dispatch (xcd = blockIdx % 8) -> each XCD owns one contiguous chunk range.
// ---------------------------------------------------------------------------
__device__ __forceinline__ int xcd_chunk_swizzle(int b) {
    const int qc = NBLK / NXCD;          // 312
    const int rc = NBLK % NXCD;          // 4
    int xcd = b % NXCD;
    int idx = b / NXCD;
    int start = (xcd < rc) ? xcd * (qc + 1) : rc * (qc + 1) + (xcd - rc) * qc;
    return start + idx;
}

// ---------------------------------------------------------------------------
// Pack W[27][32][32] f32 into MFMA B-fragment order (bf16); zero the stats
// accumulators (stream order guarantees completion before conv's atomics).
// frag (k,f): couts f*16..f*16+15; lane L reg j holds B[c=(L>>4)*8+j][d=f*16+(L&15)]
// ---------------------------------------------------------------------------
__global__ void pack_weights(const float* __restrict__ w, u16* __restrict__ wp,
                             float* __restrict__ stats) {
    int tid = blockIdx.x * blockDim.x + threadIdx.x;   // 27648
    if (blockIdx.x < 8) {
        // zero 64 slots * 8 copies * 16 floats = 8192 floats (32 KB)
        int t = blockIdx.x * 1024 + threadIdx.x;
        stats[t] = 0.f; stats[t + 256] = 0.f; stats[t + 512] = 0.f; stats[t + 768] = 0.f;
    }
    if (tid >= KOFF * 2 * 64 * 8) return;
    int j = tid & 7;
    int L = (tid >> 3) & 63;
    int f = (tid >> 9) & 1;
    int k = tid >> 10;
    int c = ((L >> 4) << 3) + j;
    int d = (f << 4) + (L & 15);
    __bf16 b = (__bf16)w[(k * 32 + c) * 32 + d];
    wp[tid] = __builtin_bit_cast(u16, b);
}

// ---------------------------------------------------------------------------
// Sparse conv via MFMA + fused BN-stats. Each wave owns 16 voxels.
// Phase 0: preload 27 neighbor ids per lane (contiguous row, 7 vector loads).
// Phase 1: 4 batches (7,7,7,6 offsets); wave-uniform ballot skip per offset
//          (~26% taken at p=1.9% density); taken: 2 clamped dwordx4 gathers
//          -> bf16 frag -> 2 MFMAs.
// Epilogue: conv -> d_out; block-wide channel sums -> atomicAdd into
//           (channel, bid&7) padded slots.
// ---------------------------------------------------------------------------
__global__ __launch_bounds__(256, 4) void conv_f32(
    const float* __restrict__ feat,     // [N][32]
    const int*  __restrict__ nbr,       // [N][27]
    const i32x4* __restrict__ wp,       // packed B-frags
    float* __restrict__ out,            // [N][32] (d_out)
    float* __restrict__ stats)          // [64][NCOPY][SPAD]
{
    const int bid = xcd_chunk_swizzle(blockIdx.x);   // contiguous range per XCD

    const int lane  = threadIdx.x & 63;
    const int wid   = (bid * 256 + threadIdx.x) >> 6;   // 0..9999 (permuted)
    const int vbase = wid * 16;
    const int m = lane & 15;
    const int q = lane >> 4;

    // ---- phase 0: this lane's full neighbor row (registers!) ----
    const int* row = nbr + (size_t)(vbase + m) * KOFF;
    int id[27];
    *(i32x4u*)(id +  0) = *(const i32x4u*)(row +  0);
    *(i32x4u*)(id +  4) = *(const i32x4u*)(row +  4);
    *(i32x4u*)(id +  8) = *(const i32x4u*)(row +  8);
    *(i32x4u*)(id + 12) = *(const i32x4u*)(row + 12);
    *(i32x4u*)(id + 16) = *(const i32x4u*)(row + 16);
    *(i32x4u*)(id + 20) = *(const i32x4u*)(row + 20);
    *(i32x2u*)(id + 24) = *(const i32x2u*)(row + 24);
    id[26] = row[26];

    f32x4 acc0 = {}, acc1 = {};

    // ---- phase 1: 4 batches of {7,7,7,6}, ballot-gated issue then drain ----
#pragma unroll
    for (int b = 0; b < 4; ++b) {
        const int base = b * 7;
        const int cnt  = (b == 3) ? 6 : 7;
        f32x4 lo[7], hi[7];
#pragma unroll
        for (int j = 0; j < 7; ++j) {
            if (j < cnt) {
                int k = base + j;
                if (__ballot(id[k] >= 0)) {        // wave-uniform scalar branch
                    int v_id = id[k];
                    int safe = v_id >= 0 ? v_id : 0;   // invalid -> hot row 0
                    const f32x4* fp = (const f32x4*)(feat + (size_t)safe * 32 + q * 8);
                    lo[j] = fp[0];
                    hi[j] = fp[1];
                }
            }
        }
#pragma unroll
        for (int j = 0; j < 7; ++j) {
            if (j < cnt) {
                int k = base + j;
                if (__ballot(id[k] >= 0)) {
                    bf16x8 t;
#pragma unroll
                    for (int jj = 0; jj < 4; ++jj) {
                        t[jj]     = (__bf16)lo[j][jj];
                        t[4 + jj] = (__bf16)hi[j][jj];
                    }
                    bf16x8 z = {};
                    bf16x8 a = (id[k] < 0) ? z : t;
                    i32x4 b0r = wp[(k * 2 + 0) * 64 + lane];
                    i32x4 b1r = wp[(k * 2 + 1) * 64 + lane];
                    bf16x8 b0 = __builtin_bit_cast(bf16x8, b0r);
                    bf16x8 b1 = __builtin_bit_cast(bf16x8, b1r);
                    acc0 = __builtin_amdgcn_mfma_f32_16x16x32_bf16(a, b0, acc0, 0, 0, 0);
                    acc1 = __builtin_amdgcn_mfma_f32_16x16x32_bf16(a, b1, acc1, 0, 0, 0);
                }
            }
        }
    }

    // ---- epilogue: store conv + per-channel stats ----
    // C/D: row(voxel) = q*4 + r, col(cout) = m (+16 for acc1)
    float s0 = 0, s1 = 0, sq0 = 0, sq1 = 0;
#pragma unroll
    for (int r = 0; r < 4; ++r) {
        int v = vbase + q * 4 + r;
        float x0 = acc0[r], x1 = acc1[r];
        s0 += x0; sq0 += x0 * x0;
        s1 += x1; sq1 += x1 * x1;
        out[v * 32 + m]      = x0;
        out[v * 32 + 16 + m] = x1;
    }
    // reduce over q (lanes sharing m)
    s0  += __shfl_xor(s0, 16, 64);  s0  += __shfl_xor(s0, 32, 64);
    s1  += __shfl_xor(s1, 16, 64);  s1  += __shfl_xor(s1, 32, 64);
    sq0 += __shfl_xor(sq0, 16, 64); sq0 += __shfl_xor(sq0, 32, 64);
    sq1 += __shfl_xor(sq1, 16, 64); sq1 += __shfl_xor(sq1, 32, 64);

    __shared__ float red[4][64];
    int w = threadIdx.x >> 6;
    if (lane < 16) {
        red[w][m]      = s0;   // sum, ch m
        red[w][16 + m] = s1;   // sum, ch 16+m
        red[w][32 + m] = sq0;  // sumsq, ch m
        red[w][48 + m] = sq1;  // sumsq, ch 16+m
    }
    __syncthreads();
    if (threadIdx.x < 64) {
        int t = threadIdx.x;
        float v = red[0][t] + red[1][t] + red[2][t] + red[3][t];
        // slot (t, bid&7), own 64 B line -> parallel chains of depth ~313
        atomicAdd(&stats[((size_t)t * NCOPY + (bid & (NCOPY - 1))) * SPAD], v);
    }
}

// ---------------------------------------------------------------------------
// BN + LeakyReLU over d_out, in place. SAME chunked swizzle as conv: block
// processes the 64-voxel chunk conv produced on this XCD -> reads are local
// L2 hits instead of cross-XCD LLC/HBM misses.
// ---------------------------------------------------------------------------
__global__ __launch_bounds__(256) void apply_bn(
    f32x4* __restrict__ o, const float* __restrict__ stats,
    const float* __restrict__ gamma, const float* __restrict__ beta)
{
    const int bid = xcd_chunk_swizzle(blockIdx.x);

    __shared__ float s[64];
    int t = threadIdx.x;
    if (t < 32) {
        float sum = 0.f, sumsq = 0.f;
#pragma unroll
        for (int c = 0; c < NCOPY; ++c) {
            sum   += stats[((size_t)t * NCOPY + c) * SPAD];
            sumsq += stats[((size_t)(32 + t) * NCOPY + c) * SPAD];
        }
        float mean = sum * (1.f / NVOX);
        float var  = sumsq * (1.f / NVOX) - mean * mean;
        float rstd = rsqrtf(var + EPSV);
        float scale = gamma[t] * rstd;
        s[t]      = scale;
        s[32 + t] = beta[t] - mean * scale;
    }
    __syncthreads();
    int i = bid * 256 + t;
#pragma unroll
    for (int rep = 0; rep < 2; ++rep) {
        int i2 = i * 2 + rep;               // 1,280,000 vec4 total
        f32x4 v = o[i2];
        int c0 = (i2 & 7) * 4;
        f32x4 r;
#pragma unroll
        for (int j = 0; j < 4; ++j) {
            float y = v[j] * s[c0 + j] + s[32 + c0 + j];
            r[j] = (y >= 0.f) ? y : SLOPE * y;
        }
        o[i2] = r;
    }
}

// ---------------------------------------------------------------------------
extern "C" void kernel_launch(void* const* d_in, const int* in_sizes, int n_in,
                              void* d_out, int out_size, void* d_ws, size_t ws_size,
                              hipStream_t stream) {
    const float* feat  = (const float*)d_in[0];  // [N][32] f32
    const int*   nbr   = (const int*)d_in[1];    // [N][27] int32
    const float* w     = (const float*)d_in[2];  // [27][32][32] f32
    // d_in[3] = bias: cancels exactly in BN — unused
    const float* gamma = (const float*)d_in[4];
    const float* beta  = (const float*)d_in[5];

    // ws layout (avoid dynamic-indexed local arrays — prior scratch lesson):
    char* ws = (char*)d_ws;
    u16*   wp    = (u16*)ws;                     // 55,296 B
    float* stats = (float*)(ws + 57344);         // 64*8 slots * 64 B = 32,768 B

    pack_weights<<<108, 256, 0, stream>>>(w, wp, stats);
    conv_f32<<<NBLK, 256, 0, stream>>>(feat, nbr, (const i32x4*)wp,
                                       (float*)d_out, stats);
    apply_bn<<<2500, 256, 0, stream>>>((f32x4*)d_out, stats, gamma, beta);
}